// Round 7
// baseline (8060.406 us; speedup 1.0000x reference)
//
#include <hip/hip_runtime.h>
#include <math.h>

#define SLEN 4096
#define DEMB 256
#define HDIM 256
#define G4   1024
#define NT   24
#define TAG_START 22
#define TAG_STOP  23
#define NEGV (-1.0e6f)
#define NINF (-3.0e38f)

// ---------------- ws layout (bytes) ----------------
// xp      : 2*4096*1024*4 = 33,554,432   @ 0
// lstm    : 4096*512*4    =  8,388,608   @ 33,554,432
// feats   : 4096*24*4     =    393,216   @ 41,943,040
// bp      : 4096*24*4     =    393,216   @ 42,336,256
//   -- first ~16.5 KiB of bp region double as LSTM scan scratch
//      (dead until K4 writes bp):
//      hfast : 2 parity x 2 dir x 256 x 8B = 8192  @ OFF_BP
//      hpub  : 2 parity x 2 dir x 256 x 8B = 8192  @ OFF_BP + 8192
//      ctrl  : cnt[8] + winner (ints)      =   64  @ OFF_BP + 16384
// maps    : 64*24*4     =      6,144   @ 42,733,568
// evec    : 64*4        =        256   @ 42,739,712
// blast   : 4           =          4   @ 42,739,968
#define OFF_XP    0
#define OFF_LSTM  33554432
#define OFF_FEATS 41943040
#define OFF_BP    42336256
#define OFF_MAPS  42733568
#define OFF_EVEC  42739712
#define OFF_BLAST 42739968

__device__ __forceinline__ float sigm_f(float x) {
    return 1.0f / (1.0f + __expf(-x));
}
__device__ __forceinline__ float tanh_f(float x) {
    // 1 - 2/(e^{2x}+1); saturates correctly for |x| large
    return 1.0f - 2.0f / (__expf(2.0f * x) + 1.0f);
}

// ------------------------------------------------------------------
// K0: zero the LSTM mailboxes + election control (16.5 KiB at OFF_BP).
// Plain kernel launch (graph-capture safe; no hipMemsetAsync anywhere).
// ------------------------------------------------------------------
__global__ __launch_bounds__(512) void init_zero_kernel(unsigned long long* __restrict__ p)
{
    int i = blockIdx.x * 512 + threadIdx.x;
    if (i < 2056) p[i] = 0ull;   // 2048 mailbox ulls + 8 control ulls
}

// ------------------------------------------------------------------
// K1: xp[dir][t][row] = emb[sent[t]] . W_ih[row] + b_ih[row] + b_hh[row]
// grid 2048 blocks (64 t-tiles x 32 row-tiles of 64), 256 threads
// ------------------------------------------------------------------
__global__ __launch_bounds__(256) void xp_gemm_kernel(
    const int* __restrict__ sent, const float* __restrict__ emb,
    const float* __restrict__ W_ih_f, const float* __restrict__ b_ih_f, const float* __restrict__ b_hh_f,
    const float* __restrict__ W_ih_b, const float* __restrict__ b_ih_b, const float* __restrict__ b_hh_b,
    float* __restrict__ xp)
{
    const int bx = blockIdx.x;
    const int tt = bx & 63;           // t tile
    const int rt = bx >> 6;           // row tile (0..31 over 2048 rows)
    const int rowbase = rt * 64;
    const int dir = rowbase >> 10;
    const int rib = rowbase & 1023;
    const float* W  = dir ? W_ih_b : W_ih_f;
    const float* bi = dir ? b_ih_b : b_ih_f;
    const float* bh = dir ? b_hh_b : b_hh_f;
    const int tid = threadIdx.x;

    __shared__ int sl[64];
    __shared__ __align__(16) float xs[16][64];
    __shared__ __align__(16) float wsd[16][64];
    if (tid < 64) sl[tid] = sent[tt * 64 + tid];
    __syncthreads();

    float acc[4][4];
#pragma unroll
    for (int i = 0; i < 4; i++)
#pragma unroll
        for (int j = 0; j < 4; j++) acc[i][j] = 0.f;

    const int tl = tid >> 2, kq = tid & 3;       // load mapping
    const int tr = tid >> 4, rc = tid & 15;      // compute mapping
    const int t0 = tr * 4, r0 = rc * 4;

    for (int kb = 0; kb < 256; kb += 16) {
        float4 xv = *(const float4*)(emb + (size_t)sl[tl] * DEMB + kb + kq * 4);
        float4 wv = *(const float4*)(W + (size_t)(rib + tl) * DEMB + kb + kq * 4);
        xs[kq*4+0][tl] = xv.x; xs[kq*4+1][tl] = xv.y; xs[kq*4+2][tl] = xv.z; xs[kq*4+3][tl] = xv.w;
        wsd[kq*4+0][tl] = wv.x; wsd[kq*4+1][tl] = wv.y; wsd[kq*4+2][tl] = wv.z; wsd[kq*4+3][tl] = wv.w;
        __syncthreads();
#pragma unroll
        for (int k = 0; k < 16; k++) {
            float4 a = *(const float4*)&xs[k][t0];
            float4 b = *(const float4*)&wsd[k][r0];
            acc[0][0] += a.x*b.x; acc[0][1] += a.x*b.y; acc[0][2] += a.x*b.z; acc[0][3] += a.x*b.w;
            acc[1][0] += a.y*b.x; acc[1][1] += a.y*b.y; acc[1][2] += a.y*b.z; acc[1][3] += a.y*b.w;
            acc[2][0] += a.z*b.x; acc[2][1] += a.z*b.y; acc[2][2] += a.z*b.z; acc[2][3] += a.z*b.w;
            acc[3][0] += a.w*b.x; acc[3][1] += a.w*b.y; acc[3][2] += a.w*b.z; acc[3][3] += a.w*b.w;
        }
        __syncthreads();
    }

#pragma unroll
    for (int jj = 0; jj < 4; jj++) {
        float bsum = bi[rib + r0 + jj] + bh[rib + r0 + jj];
        acc[0][jj] += bsum; acc[1][jj] += bsum; acc[2][jj] += bsum; acc[3][jj] += bsum;
    }
#pragma unroll
    for (int i = 0; i < 4; i++) {
        int t = tt * 64 + t0 + i;
        float4 o; o.x = acc[i][0]; o.y = acc[i][1]; o.z = acc[i][2]; o.w = acc[i][3];
        *(float4*)(xp + ((size_t)dir * SLEN + t) * G4 + rib + r0) = o;
    }
}

// ------------------------------------------------------------------
// K2: persistent LSTM scan with MEASURED XCD co-location.
//
// Role election: 128 blocks; tid0 reads HW_REG_XCC_ID, tickets a
// per-XCD counter; the XCD that first collects 16 tickets wins; its 16
// ticket holders become the roles (dir=slot>>3, s=slot&7) — all 16
// verifiably share ONE XCD / ONE L2. Deadlock-free by pigeonhole.
//
// Exchange per element = dual mailbox:
//   hfast: SC0 store (write-through to the shared L2 — round-2 evidence:
//          sc0 stores are visible beyond the producer CU; plain stores
//          (rounds 3-5) never were) read by sc0 loads (L1-bypass,
//          L2-read). Same-L2 producer/consumer => fresh at ~200cy.
//          This is the one untested {store,load,placement} cell.
//   hpub : agent-scope atomic store/load — always-correct fallback.
// Consumer per step: <=8 sc0 polls of hfast; on miss, agent poll of
// hpub. Cumulative misses > 48 disable the fast path permanently
// (worst-case transient ~35us, then steady == agent baseline).
//
// Parity double-buffer (slot = (tag&1)*512 + dir*256 + e) prevents a
// producer from recycling a slot before all consumers read it.
//
// GATE ROLE = OWN-SLICE THREADS (tid in [s*32, s*32+32)): they never
// poll, so no s_waitcnt vmcnt(0) lands on the gate->publish critical
// path, and their xp prefetch gets a full step of slack.
// ------------------------------------------------------------------
__global__ __launch_bounds__(512) void lstm_scan_kernel(
    const float* __restrict__ xp, const float* __restrict__ h0, const float* __restrict__ c0,
    const float* __restrict__ W_hh_f, const float* __restrict__ W_hh_b,
    float* __restrict__ lstm_out,
    unsigned long long* __restrict__ hfast, unsigned long long* __restrict__ hpub,
    int* __restrict__ ctrl)
{
    const int tid = threadIdx.x;

    __shared__ int role_sh;
    if (tid == 0) {
        unsigned xcc;
        asm volatile("s_getreg_b32 %0, hwreg(HW_REG_XCC_ID)" : "=s"(xcc));
        xcc &= 7u;
        int slot = __hip_atomic_fetch_add(&ctrl[xcc], 1,
                                          __ATOMIC_RELAXED, __HIP_MEMORY_SCOPE_AGENT);
        int role = -1;
        if (slot < 16) {
            if (slot == 15) {
                int expect = 0;
                __hip_atomic_compare_exchange_strong(&ctrl[8], &expect, (int)xcc + 1,
                    __ATOMIC_RELAXED, __ATOMIC_RELAXED, __HIP_MEMORY_SCOPE_AGENT);
            }
            int w;
            do {
                w = __hip_atomic_load(&ctrl[8], __ATOMIC_RELAXED, __HIP_MEMORY_SCOPE_AGENT);
            } while (w == 0);
            if (w == (int)xcc + 1) role = slot;
        }
        role_sh = role;
    }
    __syncthreads();
    const int role = role_sh;
    if (role < 0) return;              // non-elected blocks exit

    const int dir = role >> 3;
    const int s   = role & 7;          // slice 0..7

    const int wave = tid >> 6, lane = tid & 63;
    const int q = wave & 3, rgrp = wave >> 2;
    const int row_local = rgrp * 64 + lane;          // 0..127
    const int row_global = ((row_local >> 5) << 8) + s * 32 + (row_local & 31); // 0..1023

    __shared__ __align__(16) float h_lds[256];
    __shared__ float red[128][5];                    // +1 pad: conflict-free

    const float* Whh = dir ? W_hh_b : W_hh_f;
    float wreg[64];
    {
        const float4* wr = (const float4*)(Whh + (size_t)row_global * HDIM + q * 64);
#pragma unroll
        for (int i = 0; i < 16; i++) {
            float4 v = wr[i];
            wreg[4*i] = v.x; wreg[4*i+1] = v.y; wreg[4*i+2] = v.z; wreg[4*i+3] = v.w;
        }
    }

    const int own_lo = s * 32;
    const int gt = tid - own_lo;                 // gate index if 0 <= gt < 32
    const bool is_gate = (gt >= 0) && (gt < 32);

    float c_state = 0.f;
    float xp4[4] = {0.f, 0.f, 0.f, 0.f};
    if (is_gate) {
        c_state = c0[dir * HDIM + own_lo + gt];
        int tpos0 = dir ? (SLEN - 1) : 0;
        const float* base = xp + ((size_t)dir * SLEN + tpos0) * G4;
#pragma unroll
        for (int g = 0; g < 4; g++) xp4[g] = base[(g << 8) + own_lo + gt];
    }

    int use_fast = 1, miss_cnt = 0;

    for (int t = 0; t < SLEN; ++t) {
        // ---- obtain h_{t-1} ----
        if (tid < 256) {
            if (t == 0) {
                h_lds[tid] = h0[dir * HDIM + tid];
            } else if (!is_gate) {               // own slice pre-written at publish
                const unsigned want = (unsigned)t;
                const int par = t & 1;
                unsigned long long v = 0;
                int got = 0;
                if (use_fast) {
                    const unsigned long long* pf = hfast + dir * 256 + par * 512 + tid;
#pragma unroll 1
                    for (int k = 0; k < 8; ++k) {
                        unsigned long long fv;
                        asm volatile("global_load_dwordx2 %0, %1, off sc0\n\t"
                                     "s_waitcnt vmcnt(0)"
                                     : "=&v"(fv) : "v"(pf) : "memory");
                        if ((unsigned)(fv >> 32) == want) { v = fv; got = 1; break; }
                    }
                    if (!got && ++miss_cnt > 48) use_fast = 0;
                }
                if (!got) {
                    const unsigned long long* pa = hpub + dir * 256 + par * 512 + tid;
                    do {
                        v = __hip_atomic_load(pa, __ATOMIC_RELAXED, __HIP_MEMORY_SCOPE_AGENT);
                    } while ((unsigned)(v >> 32) != want);
                }
                h_lds[tid] = __uint_as_float((unsigned)(v & 0xffffffffull));
            }
        }
        __syncthreads();   // B1: h ready

        // ---- matvec: red[row][q] = W[row, q*64..q*64+64) . h ----
        float a0 = 0.f, a1 = 0.f, a2 = 0.f, a3 = 0.f;
        {
            const float4* h4 = (const float4*)&h_lds[q * 64];
#pragma unroll
            for (int i = 0; i < 16; i++) {
                float4 hv = h4[i];
                a0 += wreg[4*i]   * hv.x;
                a1 += wreg[4*i+1] * hv.y;
                a2 += wreg[4*i+2] * hv.z;
                a3 += wreg[4*i+3] * hv.w;
            }
        }
        red[row_local][q] = (a0 + a1) + (a2 + a3);
        __syncthreads();   // B2: partials ready

        if (is_gate) {
            float pre[4];
#pragma unroll
            for (int g = 0; g < 4; g++) {
                int rl = g * 32 + gt;
                pre[g] = ((red[rl][0] + red[rl][1]) + (red[rl][2] + red[rl][3])) + xp4[g];
            }
            float iv  = sigm_f(pre[0]);
            float fvv = sigm_f(pre[1]);
            float gv  = tanh_f(pre[2]);
            float ov  = sigm_f(pre[3]);
            c_state = fvv * c_state + iv * gv;
            float h = ov * tanh_f(c_state);
            int hglob = own_lo + gt;
            int tpos = dir ? (SLEN - 1 - t) : t;
            lstm_out[(size_t)tpos * 512 + dir * HDIM + hglob] = h;
            h_lds[hglob] = h;                          // own slice for next step
            const unsigned tag = (unsigned)(t + 1);
            const int ppar = (t + 1) & 1;
            unsigned long long pv = ((unsigned long long)tag << 32)
                                  | (unsigned long long)__float_as_uint(h);
            unsigned long long* pf = hfast + dir * 256 + ppar * 512 + hglob;
            asm volatile("global_store_dwordx2 %0, %1, off sc0"
                         :: "v"(pf), "v"(pv) : "memory");   // sc0: write-through to shared L2
            __hip_atomic_store(hpub + dir * 256 + ppar * 512 + hglob, pv,
                               __ATOMIC_RELAXED, __HIP_MEMORY_SCOPE_AGENT);
            // prefetch next xp rows (a full step of slack before use)
            if ((t + 1) < SLEN) {
                int tpos1 = dir ? (SLEN - 2 - t) : (t + 1);
                const float* base = xp + ((size_t)dir * SLEN + tpos1) * G4;
#pragma unroll
                for (int g = 0; g < 4; g++) xp4[g] = base[(g << 8) + own_lo + gt];
            }
        }
    }
}

// ------------------------------------------------------------------
// K3: feats[t][n] = lstm[t] . W_out[n] + b_out[n]
// ------------------------------------------------------------------
__global__ __launch_bounds__(256) void feats_kernel(
    const float* __restrict__ lstm, const float* __restrict__ W_out,
    const float* __restrict__ b_out, float* __restrict__ feats)
{
    int gid = blockIdx.x * 256 + threadIdx.x;
    if (gid >= SLEN * NT) return;
    int t = gid / NT, n = gid - t * NT;
    const float4* hr = (const float4*)(lstm + (size_t)t * 512);
    const float4* wr = (const float4*)(W_out + (size_t)n * 512);
    float acc = 0.f;
#pragma unroll 8
    for (int k = 0; k < 128; k++) {
        float4 a = hr[k], b = wr[k];
        acc += a.x * b.x + a.y * b.y + a.z * b.z + a.w * b.w;
    }
    feats[gid] = acc + b_out[n];
}

// ------------------------------------------------------------------
// K4: sequential Viterbi forward. 1 block, 64 threads (lanes 0..23 live).
// Inner max over prev tags via LDS broadcast (6 float4 reads) — same
// ascending-p strict-> first-max semantics as np.argmax.
// ------------------------------------------------------------------
__global__ __launch_bounds__(64) void viterbi_fwd_kernel(
    const float* __restrict__ feats, const float* __restrict__ trans,
    int* __restrict__ bp, float* __restrict__ score_out, int* __restrict__ blast)
{
    int lane = threadIdx.x;
    __shared__ __align__(16) float fvs[32];
    float Trow[NT];
    float tstop = NINF;
    float fv;
    if (lane < NT) {
#pragma unroll
        for (int p = 0; p < NT; p++) Trow[p] = trans[lane * NT + p];
        tstop = trans[TAG_STOP * NT + lane];
        fv = (lane == TAG_START) ? 0.f : NEGV;
    } else {
        fv = NINF;
#pragma unroll
        for (int p = 0; p < NT; p++) Trow[p] = NINF;
    }
    float fnext = (lane < NT) ? feats[lane] : 0.f;
    for (int t = 0; t < SLEN; t++) {
        float featv = fnext;
        if ((t + 1) < SLEN && lane < NT) fnext = feats[(t + 1) * NT + lane];
        if (lane < NT) fvs[lane] = fv;
        __syncthreads();               // 1 wave: cheap; orders write -> read
        float best = NINF; int arg = 0;
#pragma unroll
        for (int pq = 0; pq < 6; pq++) {
            float4 f4 = *(const float4*)&fvs[pq * 4];
            float sc;
            sc = f4.x + Trow[pq*4+0]; if (sc > best) { best = sc; arg = pq*4+0; }
            sc = f4.y + Trow[pq*4+1]; if (sc > best) { best = sc; arg = pq*4+1; }
            sc = f4.z + Trow[pq*4+2]; if (sc > best) { best = sc; arg = pq*4+2; }
            sc = f4.w + Trow[pq*4+3]; if (sc > best) { best = sc; arg = pq*4+3; }
        }
        if (lane < NT) bp[t * NT + lane] = arg;
        fv = best + featv;
    }
    float term = (lane < NT) ? (fv + tstop) : NINF;
    int idx = lane;
#pragma unroll
    for (int off = 32; off >= 1; off >>= 1) {
        float v2 = __shfl_xor(term, off);
        int   i2 = __shfl_xor(idx, off);
        if (v2 > term || (v2 == term && i2 < idx)) { term = v2; idx = i2; }
    }
    if (lane == 0) { score_out[0] = term; blast[0] = idx; }
}

// ------------------------------------------------------------------
// K5: per-chunk composed backtrace maps. 64 chunks x 64 steps.
// ------------------------------------------------------------------
__global__ __launch_bounds__(64) void bt_maps_kernel(
    const int* __restrict__ bp, int* __restrict__ maps)
{
    int c = blockIdx.x;
    __shared__ int bpl[64 * NT];
    for (int idx = threadIdx.x; idx < 64 * NT; idx += 64) bpl[idx] = bp[c * 64 * NT + idx];
    __syncthreads();
    if (threadIdx.x < NT) {
        int f = threadIdx.x;
#pragma unroll 1
        for (int k = 63; k >= 0; k--) f = bpl[k * NT + f];
        maps[c * NT + threadIdx.x] = f;
    }
}

// ------------------------------------------------------------------
// K6: combine chunk maps sequentially. evec[c] = path[64c+63].
// ------------------------------------------------------------------
__global__ __launch_bounds__(64) void bt_combine_kernel(
    const int* __restrict__ maps, const int* __restrict__ blast, int* __restrict__ evec)
{
    __shared__ int ml[64 * NT];
    for (int idx = threadIdx.x; idx < 64 * NT; idx += 64) ml[idx] = maps[idx];
    __syncthreads();
    if (threadIdx.x == 0) {
        int e = blast[0];
        evec[63] = e;
        for (int c = 63; c >= 1; c--) { e = ml[c * NT + e]; evec[c - 1] = e; }
    }
}

// ------------------------------------------------------------------
// K7: re-expand each chunk and emit path tags as floats.
// ------------------------------------------------------------------
__global__ __launch_bounds__(64) void bt_emit_kernel(
    const int* __restrict__ bp, const int* __restrict__ evec, float* __restrict__ out_path)
{
    int c = blockIdx.x;
    __shared__ int bpl[64 * NT];
    for (int idx = threadIdx.x; idx < 64 * NT; idx += 64) bpl[idx] = bp[c * 64 * NT + idx];
    __syncthreads();
    if (threadIdx.x == 0) {
        int f = evec[c];
        out_path[c * 64 + 63] = (float)f;
        for (int t = 62; t >= 0; t--) {
            f = bpl[(t + 1) * NT + f];
            out_path[c * 64 + t] = (float)f;
        }
    }
}

extern "C" void kernel_launch(void* const* d_in, const int* in_sizes, int n_in,
                              void* d_out, int out_size, void* d_ws, size_t ws_size,
                              hipStream_t stream)
{
    const int*   sent   = (const int*)d_in[0];
    const float* h0     = (const float*)d_in[1];
    const float* c0     = (const float*)d_in[2];
    const float* emb    = (const float*)d_in[3];
    const float* W_ih_f = (const float*)d_in[4];
    const float* W_hh_f = (const float*)d_in[5];
    const float* b_ih_f = (const float*)d_in[6];
    const float* b_hh_f = (const float*)d_in[7];
    const float* W_ih_b = (const float*)d_in[8];
    const float* W_hh_b = (const float*)d_in[9];
    const float* b_ih_b = (const float*)d_in[10];
    const float* b_hh_b = (const float*)d_in[11];
    const float* W_out  = (const float*)d_in[12];
    const float* b_out  = (const float*)d_in[13];
    const float* trans  = (const float*)d_in[14];

    char* ws = (char*)d_ws;
    float* xp    = (float*)(ws + OFF_XP);
    float* lstm  = (float*)(ws + OFF_LSTM);
    float* feats = (float*)(ws + OFF_FEATS);
    int*   bp    = (int*)  (ws + OFF_BP);
    unsigned long long* hfast = (unsigned long long*)(ws + OFF_BP);          // 8 KiB (dead until K4)
    unsigned long long* hpub  = (unsigned long long*)(ws + OFF_BP + 8192);   // 8 KiB (dead until K4)
    int* ctrl = (int*)(ws + OFF_BP + 16384);                                 // cnt[8] + winner
    int*   maps  = (int*)  (ws + OFF_MAPS);
    int*   evec  = (int*)  (ws + OFF_EVEC);
    int*   blast = (int*)  (ws + OFF_BLAST);

    float* outf = (float*)d_out;

    init_zero_kernel<<<5, 512, 0, stream>>>(hfast);   // zeroes mailboxes + ctrl (contiguous)
    xp_gemm_kernel<<<2048, 256, 0, stream>>>(sent, emb, W_ih_f, b_ih_f, b_hh_f,
                                             W_ih_b, b_ih_b, b_hh_b, xp);
    lstm_scan_kernel<<<128, 512, 0, stream>>>(xp, h0, c0, W_hh_f, W_hh_b, lstm,
                                              hfast, hpub, ctrl);
    feats_kernel<<<384, 256, 0, stream>>>(lstm, W_out, b_out, feats);
    viterbi_fwd_kernel<<<1, 64, 0, stream>>>(feats, trans, bp, outf, blast);
    bt_maps_kernel<<<64, 64, 0, stream>>>(bp, maps);
    bt_combine_kernel<<<1, 64, 0, stream>>>(maps, blast, evec);
    bt_emit_kernel<<<64, 64, 0, stream>>>(bp, evec, outf + 1);
}

// Round 8
// 7356.960 us; speedup vs baseline: 1.0956x; 1.0956x over previous
//
#include <hip/hip_runtime.h>
#include <math.h>

#define SLEN 4096
#define DEMB 256
#define HDIM 256
#define G4   1024
#define NT   24
#define TAG_START 22
#define TAG_STOP  23
#define NEGV (-1.0e6f)
#define NINF (-3.0e38f)

// ---------------- ws layout (bytes) ----------------
// xp      : 2*4096*1024*4 = 33,554,432   @ 0
// lstm    : 4096*512*4    =  8,388,608   @ 33,554,432
// feats   : 4096*24*4     =    393,216   @ 41,943,040
// bp      : 4096*24*4     =    393,216   @ 42,336,256
//   -- first 8 KiB of bp region double as LSTM h mailboxes
//      (dead until K4 writes bp):
//      hpub : 2 parity x 2 dir x 256 x 8B = 8192 @ OFF_BP
//      slot = dir*256 + par*512 + element
// maps    : 64*24*4     =      6,144   @ 42,733,568
// evec    : 64*4        =        256   @ 42,739,712
// blast   : 4           =          4   @ 42,739,968
#define OFF_XP    0
#define OFF_LSTM  33554432
#define OFF_FEATS 41943040
#define OFF_BP    42336256
#define OFF_MAPS  42733568
#define OFF_EVEC  42739712
#define OFF_BLAST 42739968

__device__ __forceinline__ float sigm_f(float x) {
    return 1.0f / (1.0f + __expf(-x));
}
__device__ __forceinline__ float tanh_f(float x) {
    // 1 - 2/(e^{2x}+1); saturates correctly for |x| large
    return 1.0f - 2.0f / (__expf(2.0f * x) + 1.0f);
}

// ------------------------------------------------------------------
// K0: zero the LSTM mailboxes (8 KiB at OFF_BP). Plain kernel launch
// (graph-capture safe; no hipMemsetAsync anywhere).
// ------------------------------------------------------------------
__global__ __launch_bounds__(512) void init_zero_kernel(unsigned long long* __restrict__ p)
{
    int i = blockIdx.x * 512 + threadIdx.x;
    if (i < 1024) p[i] = 0ull;
}

// ------------------------------------------------------------------
// K1: xp[dir][t][row] = emb[sent[t]] . W_ih[row] + b_ih[row] + b_hh[row]
// grid 2048 blocks (64 t-tiles x 32 row-tiles of 64), 256 threads
// ------------------------------------------------------------------
__global__ __launch_bounds__(256) void xp_gemm_kernel(
    const int* __restrict__ sent, const float* __restrict__ emb,
    const float* __restrict__ W_ih_f, const float* __restrict__ b_ih_f, const float* __restrict__ b_hh_f,
    const float* __restrict__ W_ih_b, const float* __restrict__ b_ih_b, const float* __restrict__ b_hh_b,
    float* __restrict__ xp)
{
    const int bx = blockIdx.x;
    const int tt = bx & 63;           // t tile
    const int rt = bx >> 6;           // row tile (0..31 over 2048 rows)
    const int rowbase = rt * 64;
    const int dir = rowbase >> 10;
    const int rib = rowbase & 1023;
    const float* W  = dir ? W_ih_b : W_ih_f;
    const float* bi = dir ? b_ih_b : b_ih_f;
    const float* bh = dir ? b_hh_b : b_hh_f;
    const int tid = threadIdx.x;

    __shared__ int sl[64];
    __shared__ __align__(16) float xs[16][64];
    __shared__ __align__(16) float wsd[16][64];
    if (tid < 64) sl[tid] = sent[tt * 64 + tid];
    __syncthreads();

    float acc[4][4];
#pragma unroll
    for (int i = 0; i < 4; i++)
#pragma unroll
        for (int j = 0; j < 4; j++) acc[i][j] = 0.f;

    const int tl = tid >> 2, kq = tid & 3;       // load mapping
    const int tr = tid >> 4, rc = tid & 15;      // compute mapping
    const int t0 = tr * 4, r0 = rc * 4;

    for (int kb = 0; kb < 256; kb += 16) {
        float4 xv = *(const float4*)(emb + (size_t)sl[tl] * DEMB + kb + kq * 4);
        float4 wv = *(const float4*)(W + (size_t)(rib + tl) * DEMB + kb + kq * 4);
        xs[kq*4+0][tl] = xv.x; xs[kq*4+1][tl] = xv.y; xs[kq*4+2][tl] = xv.z; xs[kq*4+3][tl] = xv.w;
        wsd[kq*4+0][tl] = wv.x; wsd[kq*4+1][tl] = wv.y; wsd[kq*4+2][tl] = wv.z; wsd[kq*4+3][tl] = wv.w;
        __syncthreads();
#pragma unroll
        for (int k = 0; k < 16; k++) {
            float4 a = *(const float4*)&xs[k][t0];
            float4 b = *(const float4*)&wsd[k][r0];
            acc[0][0] += a.x*b.x; acc[0][1] += a.x*b.y; acc[0][2] += a.x*b.z; acc[0][3] += a.x*b.w;
            acc[1][0] += a.y*b.x; acc[1][1] += a.y*b.y; acc[1][2] += a.y*b.z; acc[1][3] += a.y*b.w;
            acc[2][0] += a.z*b.x; acc[2][1] += a.z*b.y; acc[2][2] += a.z*b.z; acc[2][3] += a.z*b.w;
            acc[3][0] += a.w*b.x; acc[3][1] += a.w*b.y; acc[3][2] += a.w*b.z; acc[3][3] += a.w*b.w;
        }
        __syncthreads();
    }

#pragma unroll
    for (int jj = 0; jj < 4; jj++) {
        float bsum = bi[rib + r0 + jj] + bh[rib + r0 + jj];
        acc[0][jj] += bsum; acc[1][jj] += bsum; acc[2][jj] += bsum; acc[3][jj] += bsum;
    }
#pragma unroll
    for (int i = 0; i < 4; i++) {
        int t = tt * 64 + t0 + i;
        float4 o; o.x = acc[i][0]; o.y = acc[i][1]; o.z = acc[i][2]; o.w = acc[i][3];
        *(float4*)(xp + ((size_t)dir * SLEN + t) * G4 + rib + r0) = o;
    }
}

// ------------------------------------------------------------------
// K2: persistent LSTM scan — single-barrier, per-wave column polling.
// Grid 64 x 512; roles at blockIdx%8 in {0,1} (dir=blockIdx%8,
// s=blockIdx/8) — round-4 mapping (measured faster than one-XCD
// election; rounds 2-7 falsified all L2-mailbox fast paths, so the
// exchange is agent-scope/MALL only and placement is irrelevant for
// the mailbox; spreading blocks avoids single-XCD congestion).
//
// Per step:
//   * each LANE polls ONE mailbox element (its wave's column element
//     h[q*64+lane]) with an agent-scope tagged load; deposits into a
//     PER-WAVE private LDS buffer h_priv[wave][lane]. Intra-wave
//     ds_write -> s_waitcnt lgkmcnt(0) is wave-synchronous: the wave
//     starts its matvec as soon as ITS 64 elements are fresh — no
//     global 224-poller tail, no B1 barrier.
//   * matvec into red[t&1][row][q] (parity double-buffer), ONE
//     __syncthreads (B2), then gates (tid<32) read red, compute
//     i/f/g/o + c,h, publish (agent store FIRST), write lstm_out,
//     prefetch next xp.
// Cross-step safety: h_priv is wave-private (program order). red is
// parity-buffered; a block reaches the red[par] write of step t+2 only
// after polling tags t+2, which requires every gate published t+2,
// which (transitively through tags) requires every block consumed
// step t — so gates' red[par] reads of step t are long done.
// Mailbox parity (slot = dir*256 + (tag&1)*512 + e) prevents slot
// recycling before all consumers read the previous tag (same argument).
// ------------------------------------------------------------------
__global__ __launch_bounds__(512) void lstm_scan_kernel(
    const float* __restrict__ xp, const float* __restrict__ h0, const float* __restrict__ c0,
    const float* __restrict__ W_hh_f, const float* __restrict__ W_hh_b,
    float* __restrict__ lstm_out, unsigned long long* __restrict__ hpub)
{
    const int bx = blockIdx.x;
    const int sub = bx & 7;
    if (sub >= 2) return;              // 48 of 64 blocks exit immediately
    const int dir = sub;
    const int s = bx >> 3;             // slice 0..7
    const int tid = threadIdx.x;

    const int wave = tid >> 6, lane = tid & 63;
    const int q = wave & 3, rgrp = wave >> 2;
    const int row_local = rgrp * 64 + lane;          // 0..127
    const int row_global = ((row_local >> 5) << 8) + s * 32 + (row_local & 31); // 0..1023

    __shared__ __align__(16) float h_priv[8][64];    // per-wave private column copy
    __shared__ float red[2][128][5];                 // parity dbuf, +1 pad

    const float* Whh = dir ? W_hh_b : W_hh_f;
    float wreg[64];
    {
        const float4* wr = (const float4*)(Whh + (size_t)row_global * HDIM + q * 64);
#pragma unroll
        for (int i = 0; i < 16; i++) {
            float4 v = wr[i];
            wreg[4*i] = v.x; wreg[4*i+1] = v.y; wreg[4*i+2] = v.z; wreg[4*i+3] = v.w;
        }
    }

    float c_state = 0.f;
    float xp4[4] = {0.f, 0.f, 0.f, 0.f};
    if (tid < 32) {
        c_state = c0[dir * HDIM + s * 32 + tid];
        int tpos0 = dir ? (SLEN - 1) : 0;
        const float* base = xp + ((size_t)dir * SLEN + tpos0) * G4;
#pragma unroll
        for (int g = 0; g < 4; g++) xp4[g] = base[(g << 8) + s * 32 + tid];
    }

    const int hidx = q * 64 + lane;                  // element this lane polls
    unsigned long long* mbase = hpub + dir * 256;    // + par*512 + e

    for (int t = 0; t < SLEN; ++t) {
        // ---- obtain this lane's column element of h_{t-1} ----
        float hval;
        if (t == 0) {
            hval = h0[dir * HDIM + hidx];
        } else {
            const unsigned want = (unsigned)t;
            const unsigned long long* pa = mbase + (t & 1) * 512 + hidx;
            unsigned long long v;
            do {
                v = __hip_atomic_load(pa, __ATOMIC_RELAXED, __HIP_MEMORY_SCOPE_AGENT);
            } while ((unsigned)(v >> 32) != want);
            hval = __uint_as_float((unsigned)(v & 0xffffffffull));
        }
        h_priv[wave][lane] = hval;
        asm volatile("s_waitcnt lgkmcnt(0)" ::: "memory");   // wave-sync: 64 writes done
        __builtin_amdgcn_sched_barrier(0);

        // ---- matvec: red[par][row][q] = W[row, q*64..q*64+64) . h ----
        float a0 = 0.f, a1 = 0.f, a2 = 0.f, a3 = 0.f;
        {
            const float4* h4 = (const float4*)&h_priv[wave][0];
#pragma unroll
            for (int i = 0; i < 16; i++) {
                float4 hv = h4[i];
                a0 += wreg[4*i]   * hv.x;
                a1 += wreg[4*i+1] * hv.y;
                a2 += wreg[4*i+2] * hv.z;
                a3 += wreg[4*i+3] * hv.w;
            }
        }
        red[t & 1][row_local][q] = (a0 + a1) + (a2 + a3);
        __syncthreads();   // B2: partials ready (only barrier per step)

        if (tid < 32) {
            const int par = t & 1;
            float pre[4];
#pragma unroll
            for (int g = 0; g < 4; g++) {
                int rl = g * 32 + tid;
                pre[g] = ((red[par][rl][0] + red[par][rl][1])
                        + (red[par][rl][2] + red[par][rl][3])) + xp4[g];
            }
            float iv  = sigm_f(pre[0]);
            float fvv = sigm_f(pre[1]);
            float gv  = tanh_f(pre[2]);
            float ov  = sigm_f(pre[3]);
            c_state = fvv * c_state + iv * gv;
            float h = ov * tanh_f(c_state);
            int hglob = s * 32 + tid;
            // publish FIRST (critical path), then bulk stores/prefetch
            unsigned long long pv = ((unsigned long long)(unsigned)(t + 1) << 32)
                                  | (unsigned long long)__float_as_uint(h);
            __hip_atomic_store(mbase + ((t + 1) & 1) * 512 + hglob, pv,
                               __ATOMIC_RELAXED, __HIP_MEMORY_SCOPE_AGENT);
            int tpos = dir ? (SLEN - 1 - t) : t;
            lstm_out[(size_t)tpos * 512 + dir * HDIM + hglob] = h;
            if ((t + 1) < SLEN) {
                int tpos1 = dir ? (SLEN - 2 - t) : (t + 1);
                const float* base = xp + ((size_t)dir * SLEN + tpos1) * G4;
#pragma unroll
                for (int g = 0; g < 4; g++) xp4[g] = base[(g << 8) + s * 32 + tid];
            }
        }
    }
}

// ------------------------------------------------------------------
// K3: feats[t][n] = lstm[t] . W_out[n] + b_out[n]
// ------------------------------------------------------------------
__global__ __launch_bounds__(256) void feats_kernel(
    const float* __restrict__ lstm, const float* __restrict__ W_out,
    const float* __restrict__ b_out, float* __restrict__ feats)
{
    int gid = blockIdx.x * 256 + threadIdx.x;
    if (gid >= SLEN * NT) return;
    int t = gid / NT, n = gid - t * NT;
    const float4* hr = (const float4*)(lstm + (size_t)t * 512);
    const float4* wr = (const float4*)(W_out + (size_t)n * 512);
    float acc = 0.f;
#pragma unroll 8
    for (int k = 0; k < 128; k++) {
        float4 a = hr[k], b = wr[k];
        acc += a.x * b.x + a.y * b.y + a.z * b.z + a.w * b.w;
    }
    feats[gid] = acc + b_out[n];
}

// ------------------------------------------------------------------
// K4: sequential Viterbi forward. 1 block, 64 threads (lanes 0..23 live).
// Inner max over prev tags via LDS broadcast (6 float4 reads) — same
// ascending-p strict-> first-max semantics as np.argmax.
// ------------------------------------------------------------------
__global__ __launch_bounds__(64) void viterbi_fwd_kernel(
    const float* __restrict__ feats, const float* __restrict__ trans,
    int* __restrict__ bp, float* __restrict__ score_out, int* __restrict__ blast)
{
    int lane = threadIdx.x;
    __shared__ __align__(16) float fvs[32];
    float Trow[NT];
    float tstop = NINF;
    float fv;
    if (lane < NT) {
#pragma unroll
        for (int p = 0; p < NT; p++) Trow[p] = trans[lane * NT + p];
        tstop = trans[TAG_STOP * NT + lane];
        fv = (lane == TAG_START) ? 0.f : NEGV;
    } else {
        fv = NINF;
#pragma unroll
        for (int p = 0; p < NT; p++) Trow[p] = NINF;
    }
    float fnext = (lane < NT) ? feats[lane] : 0.f;
    for (int t = 0; t < SLEN; t++) {
        float featv = fnext;
        if ((t + 1) < SLEN && lane < NT) fnext = feats[(t + 1) * NT + lane];
        if (lane < NT) fvs[lane] = fv;
        __syncthreads();               // 1 wave: cheap; orders write -> read
        float best = NINF; int arg = 0;
#pragma unroll
        for (int pq = 0; pq < 6; pq++) {
            float4 f4 = *(const float4*)&fvs[pq * 4];
            float sc;
            sc = f4.x + Trow[pq*4+0]; if (sc > best) { best = sc; arg = pq*4+0; }
            sc = f4.y + Trow[pq*4+1]; if (sc > best) { best = sc; arg = pq*4+1; }
            sc = f4.z + Trow[pq*4+2]; if (sc > best) { best = sc; arg = pq*4+2; }
            sc = f4.w + Trow[pq*4+3]; if (sc > best) { best = sc; arg = pq*4+3; }
        }
        if (lane < NT) bp[t * NT + lane] = arg;
        fv = best + featv;
    }
    float term = (lane < NT) ? (fv + tstop) : NINF;
    int idx = lane;
#pragma unroll
    for (int off = 32; off >= 1; off >>= 1) {
        float v2 = __shfl_xor(term, off);
        int   i2 = __shfl_xor(idx, off);
        if (v2 > term || (v2 == term && i2 < idx)) { term = v2; idx = i2; }
    }
    if (lane == 0) { score_out[0] = term; blast[0] = idx; }
}

// ------------------------------------------------------------------
// K5: per-chunk composed backtrace maps. 64 chunks x 64 steps.
// ------------------------------------------------------------------
__global__ __launch_bounds__(64) void bt_maps_kernel(
    const int* __restrict__ bp, int* __restrict__ maps)
{
    int c = blockIdx.x;
    __shared__ int bpl[64 * NT];
    for (int idx = threadIdx.x; idx < 64 * NT; idx += 64) bpl[idx] = bp[c * 64 * NT + idx];
    __syncthreads();
    if (threadIdx.x < NT) {
        int f = threadIdx.x;
#pragma unroll 1
        for (int k = 63; k >= 0; k--) f = bpl[k * NT + f];
        maps[c * NT + threadIdx.x] = f;
    }
}

// ------------------------------------------------------------------
// K6: combine chunk maps sequentially. evec[c] = path[64c+63].
// ------------------------------------------------------------------
__global__ __launch_bounds__(64) void bt_combine_kernel(
    const int* __restrict__ maps, const int* __restrict__ blast, int* __restrict__ evec)
{
    __shared__ int ml[64 * NT];
    for (int idx = threadIdx.x; idx < 64 * NT; idx += 64) ml[idx] = maps[idx];
    __syncthreads();
    if (threadIdx.x == 0) {
        int e = blast[0];
        evec[63] = e;
        for (int c = 63; c >= 1; c--) { e = ml[c * NT + e]; evec[c - 1] = e; }
    }
}

// ------------------------------------------------------------------
// K7: re-expand each chunk and emit path tags as floats.
// ------------------------------------------------------------------
__global__ __launch_bounds__(64) void bt_emit_kernel(
    const int* __restrict__ bp, const int* __restrict__ evec, float* __restrict__ out_path)
{
    int c = blockIdx.x;
    __shared__ int bpl[64 * NT];
    for (int idx = threadIdx.x; idx < 64 * NT; idx += 64) bpl[idx] = bp[c * 64 * NT + idx];
    __syncthreads();
    if (threadIdx.x == 0) {
        int f = evec[c];
        out_path[c * 64 + 63] = (float)f;
        for (int t = 62; t >= 0; t--) {
            f = bpl[(t + 1) * NT + f];
            out_path[c * 64 + t] = (float)f;
        }
    }
}

extern "C" void kernel_launch(void* const* d_in, const int* in_sizes, int n_in,
                              void* d_out, int out_size, void* d_ws, size_t ws_size,
                              hipStream_t stream)
{
    const int*   sent   = (const int*)d_in[0];
    const float* h0     = (const float*)d_in[1];
    const float* c0     = (const float*)d_in[2];
    const float* emb    = (const float*)d_in[3];
    const float* W_ih_f = (const float*)d_in[4];
    const float* W_hh_f = (const float*)d_in[5];
    const float* b_ih_f = (const float*)d_in[6];
    const float* b_hh_f = (const float*)d_in[7];
    const float* W_ih_b = (const float*)d_in[8];
    const float* W_hh_b = (const float*)d_in[9];
    const float* b_ih_b = (const float*)d_in[10];
    const float* b_hh_b = (const float*)d_in[11];
    const float* W_out  = (const float*)d_in[12];
    const float* b_out  = (const float*)d_in[13];
    const float* trans  = (const float*)d_in[14];

    char* ws = (char*)d_ws;
    float* xp    = (float*)(ws + OFF_XP);
    float* lstm  = (float*)(ws + OFF_LSTM);
    float* feats = (float*)(ws + OFF_FEATS);
    int*   bp    = (int*)  (ws + OFF_BP);
    unsigned long long* hpub = (unsigned long long*)(ws + OFF_BP);   // 8 KiB (dead until K4)
    int*   maps  = (int*)  (ws + OFF_MAPS);
    int*   evec  = (int*)  (ws + OFF_EVEC);
    int*   blast = (int*)  (ws + OFF_BLAST);

    float* outf = (float*)d_out;

    init_zero_kernel<<<2, 512, 0, stream>>>(hpub);    // zero 1024 mailbox slots
    xp_gemm_kernel<<<2048, 256, 0, stream>>>(sent, emb, W_ih_f, b_ih_f, b_hh_f,
                                             W_ih_b, b_ih_b, b_hh_b, xp);
    lstm_scan_kernel<<<64, 512, 0, stream>>>(xp, h0, c0, W_hh_f, W_hh_b, lstm, hpub);
    feats_kernel<<<384, 256, 0, stream>>>(lstm, W_out, b_out, feats);
    viterbi_fwd_kernel<<<1, 64, 0, stream>>>(feats, trans, bp, outf, blast);
    bt_maps_kernel<<<64, 64, 0, stream>>>(bp, maps);
    bt_combine_kernel<<<1, 64, 0, stream>>>(maps, blast, evec);
    bt_emit_kernel<<<64, 64, 0, stream>>>(bp, evec, outf + 1);
}

// Round 9
// 7201.842 us; speedup vs baseline: 1.1192x; 1.0215x over previous
//
#include <hip/hip_runtime.h>
#include <math.h>

#define SLEN 4096
#define DEMB 256
#define HDIM 256
#define G4   1024
#define NT   24
#define TAG_START 22
#define TAG_STOP  23
#define NEGV (-1.0e6f)
#define NINF (-3.0e38f)

// ---------------- ws layout (bytes) ----------------
// xp      : 2*4096*1024*4 = 33,554,432   @ 0
// lstm    : 4096*512*4    =  8,388,608   @ 33,554,432
// feats   : 4096*24*4     =    393,216   @ 41,943,040
// bp      : 4096*24*4     =    393,216   @ 42,336,256
//   -- first 8 KiB of bp region double as LSTM h mailboxes
//      (dead until K4 writes bp):
//      hpub : 2 parity x 2 dir x 256 x 8B = 8192 @ OFF_BP
//      slot = dir*256 + par*512 + element
// maps    : 64*24*4     =      6,144   @ 42,733,568
// evec    : 64*4        =        256   @ 42,739,712
// blast   : 4           =          4   @ 42,739,968
#define OFF_XP    0
#define OFF_LSTM  33554432
#define OFF_FEATS 41943040
#define OFF_BP    42336256
#define OFF_MAPS  42733568
#define OFF_EVEC  42739712
#define OFF_BLAST 42739968

__device__ __forceinline__ float sigm_f(float x) {
    return 1.0f / (1.0f + __expf(-x));
}
__device__ __forceinline__ float tanh_f(float x) {
    // 1 - 2/(e^{2x}+1); saturates correctly for |x| large
    return 1.0f - 2.0f / (__expf(2.0f * x) + 1.0f);
}

// ------------------------------------------------------------------
// K0: zero the LSTM mailboxes (8 KiB at OFF_BP). Plain kernel launch
// (graph-capture safe; no hipMemsetAsync anywhere).
// ------------------------------------------------------------------
__global__ __launch_bounds__(512) void init_zero_kernel(unsigned long long* __restrict__ p)
{
    int i = blockIdx.x * 512 + threadIdx.x;
    if (i < 1024) p[i] = 0ull;
}

// ------------------------------------------------------------------
// K1: xp[dir][t][row] = emb[sent[t]] . W_ih[row] + b_ih[row] + b_hh[row]
// grid 2048 blocks (64 t-tiles x 32 row-tiles of 64), 256 threads
// ------------------------------------------------------------------
__global__ __launch_bounds__(256) void xp_gemm_kernel(
    const int* __restrict__ sent, const float* __restrict__ emb,
    const float* __restrict__ W_ih_f, const float* __restrict__ b_ih_f, const float* __restrict__ b_hh_f,
    const float* __restrict__ W_ih_b, const float* __restrict__ b_ih_b, const float* __restrict__ b_hh_b,
    float* __restrict__ xp)
{
    const int bx = blockIdx.x;
    const int tt = bx & 63;           // t tile
    const int rt = bx >> 6;           // row tile (0..31 over 2048 rows)
    const int rowbase = rt * 64;
    const int dir = rowbase >> 10;
    const int rib = rowbase & 1023;
    const float* W  = dir ? W_ih_b : W_ih_f;
    const float* bi = dir ? b_ih_b : b_ih_f;
    const float* bh = dir ? b_hh_b : b_hh_f;
    const int tid = threadIdx.x;

    __shared__ int sl[64];
    __shared__ __align__(16) float xs[16][64];
    __shared__ __align__(16) float wsd[16][64];
    if (tid < 64) sl[tid] = sent[tt * 64 + tid];
    __syncthreads();

    float acc[4][4];
#pragma unroll
    for (int i = 0; i < 4; i++)
#pragma unroll
        for (int j = 0; j < 4; j++) acc[i][j] = 0.f;

    const int tl = tid >> 2, kq = tid & 3;       // load mapping
    const int tr = tid >> 4, rc = tid & 15;      // compute mapping
    const int t0 = tr * 4, r0 = rc * 4;

    for (int kb = 0; kb < 256; kb += 16) {
        float4 xv = *(const float4*)(emb + (size_t)sl[tl] * DEMB + kb + kq * 4);
        float4 wv = *(const float4*)(W + (size_t)(rib + tl) * DEMB + kb + kq * 4);
        xs[kq*4+0][tl] = xv.x; xs[kq*4+1][tl] = xv.y; xs[kq*4+2][tl] = xv.z; xs[kq*4+3][tl] = xv.w;
        wsd[kq*4+0][tl] = wv.x; wsd[kq*4+1][tl] = wv.y; wsd[kq*4+2][tl] = wv.z; wsd[kq*4+3][tl] = wv.w;
        __syncthreads();
#pragma unroll
        for (int k = 0; k < 16; k++) {
            float4 a = *(const float4*)&xs[k][t0];
            float4 b = *(const float4*)&wsd[k][r0];
            acc[0][0] += a.x*b.x; acc[0][1] += a.x*b.y; acc[0][2] += a.x*b.z; acc[0][3] += a.x*b.w;
            acc[1][0] += a.y*b.x; acc[1][1] += a.y*b.y; acc[1][2] += a.y*b.z; acc[1][3] += a.y*b.w;
            acc[2][0] += a.z*b.x; acc[2][1] += a.z*b.y; acc[2][2] += a.z*b.z; acc[2][3] += a.z*b.w;
            acc[3][0] += a.w*b.x; acc[3][1] += a.w*b.y; acc[3][2] += a.w*b.z; acc[3][3] += a.w*b.w;
        }
        __syncthreads();
    }

#pragma unroll
    for (int jj = 0; jj < 4; jj++) {
        float bsum = bi[rib + r0 + jj] + bh[rib + r0 + jj];
        acc[0][jj] += bsum; acc[1][jj] += bsum; acc[2][jj] += bsum; acc[3][jj] += bsum;
    }
#pragma unroll
    for (int i = 0; i < 4; i++) {
        int t = tt * 64 + t0 + i;
        float4 o; o.x = acc[i][0]; o.y = acc[i][1]; o.z = acc[i][2]; o.w = acc[i][3];
        *(float4*)(xp + ((size_t)dir * SLEN + t) * G4 + rib + r0) = o;
    }
}

// ------------------------------------------------------------------
// K2: persistent LSTM scan — dedicated gate wave, off-critical-path tail.
// Grid 64 x 576 (9 waves); roles at blockIdx%8 in {0,1}
// (dir=blockIdx%8, s=blockIdx/8), spread across XCDs (r4 mapping;
// rounds 2-7 falsified all L2-mailbox fast paths -> exchange is
// agent-scope/MALL; single-XCD concentration measured slower).
//
// Waves 0-7 (matvec consumers): per-lane poll of ONE mailbox element
//   (hidx = q*64+lane, agent-scope tagged load) -> h_priv[wave] (wave-
//   private LDS, no barrier needed; intra-wave lgkmcnt suffices) ->
//   64-FMA matvec -> red[t&1][row][q] -> __syncthreads -> next t.
//   They NEVER publish and carry no gate state: their next poll starts
//   immediately after the barrier.
// Wave 8, lanes<32 (gate producer): __syncthreads -> read red[t&1]
//   (stride-5 rows: conflict-free) -> gates -> c,h -> PUBLISH FIRST
//   (agent store, tag t+1) -> lstm_out store + xp prefetch AFTER
//   (off critical path; no polling in this wave => no vmcnt(0) ever
//   drains its prefetch — round-3 lesson).
//
// This removes r8's mistake: there the gate threads also polled, so
// the gate tail (~400cy) sat serially between publish(t) and the next
// detect. Now critical path = detect + matvec + B2 + (red-read+gates+
// publish-issue).
//
// Safety: barrier counts match (1/iter/role). red parity dbuf:
// gate reads red[t&1] while matvec writes red[(t+1)&1]; matvec re-
// writes red[t&1] only after barrier t+1, which gate reaches after
// finishing its reads. Mailbox parity recycling: block A overwrites
// tag t+1 (publishing t+3) only after A consumed t+2 <- every block
// published t+2 <- their barrier(t+1) <- their consumers consumed
// t+1. Tags start at 1; mailboxes zeroed by K0.
// ------------------------------------------------------------------
__global__ __launch_bounds__(576) void lstm_scan_kernel(
    const float* __restrict__ xp, const float* __restrict__ h0, const float* __restrict__ c0,
    const float* __restrict__ W_hh_f, const float* __restrict__ W_hh_b,
    float* __restrict__ lstm_out, unsigned long long* __restrict__ hpub)
{
    const int bx = blockIdx.x;
    const int sub = bx & 7;
    if (sub >= 2) return;              // 48 of 64 blocks exit immediately
    const int dir = sub;
    const int s = bx >> 3;             // slice 0..7
    const int tid = threadIdx.x;
    const int wave = tid >> 6, lane = tid & 63;

    __shared__ __align__(16) float h_priv[8][64];    // per-wave private h copy
    __shared__ float red[2][128][5];                 // parity dbuf, +1 pad

    unsigned long long* mbase = hpub + dir * 256;    // + par*512 + element

    if (wave < 8) {
        // ---------------- matvec consumer role ----------------
        const int q = wave & 3, rgrp = wave >> 2;
        const int row_local = rgrp * 64 + lane;          // 0..127
        const int row_global = ((row_local >> 5) << 8) + s * 32 + (row_local & 31);
        const float* Whh = dir ? W_hh_b : W_hh_f;
        float wreg[64];
        {
            const float4* wr = (const float4*)(Whh + (size_t)row_global * HDIM + q * 64);
#pragma unroll
            for (int i = 0; i < 16; i++) {
                float4 v = wr[i];
                wreg[4*i] = v.x; wreg[4*i+1] = v.y; wreg[4*i+2] = v.z; wreg[4*i+3] = v.w;
            }
        }
        const int hidx = q * 64 + lane;

        for (int t = 0; t < SLEN; ++t) {
            float hval;
            if (t == 0) {
                hval = h0[dir * HDIM + hidx];
            } else {
                const unsigned want = (unsigned)t;
                const unsigned long long* pa = mbase + (t & 1) * 512 + hidx;
                unsigned long long v;
                do {
                    v = __hip_atomic_load(pa, __ATOMIC_RELAXED, __HIP_MEMORY_SCOPE_AGENT);
                } while ((unsigned)(v >> 32) != want);
                hval = __uint_as_float((unsigned)(v & 0xffffffffull));
            }
            h_priv[wave][lane] = hval;
            asm volatile("s_waitcnt lgkmcnt(0)" ::: "memory");  // wave-sync
            __builtin_amdgcn_sched_barrier(0);

            float a0 = 0.f, a1 = 0.f, a2 = 0.f, a3 = 0.f;
            {
                const float4* h4 = (const float4*)&h_priv[wave][0];
#pragma unroll
                for (int i = 0; i < 16; i++) {
                    float4 hv = h4[i];
                    a0 += wreg[4*i]   * hv.x;
                    a1 += wreg[4*i+1] * hv.y;
                    a2 += wreg[4*i+2] * hv.z;
                    a3 += wreg[4*i+3] * hv.w;
                }
            }
            red[t & 1][row_local][q] = (a0 + a1) + (a2 + a3);
            __syncthreads();   // barrier #t
        }
    } else {
        // ---------------- gate producer role (wave 8) ----------------
        const bool act = (lane < 32);
        float c_state = 0.f;
        float xp4[4] = {0.f, 0.f, 0.f, 0.f};
        if (act) {
            c_state = c0[dir * HDIM + s * 32 + lane];
            int tpos0 = dir ? (SLEN - 1) : 0;
            const float* base = xp + ((size_t)dir * SLEN + tpos0) * G4;
#pragma unroll
            for (int g = 0; g < 4; g++) xp4[g] = base[(g << 8) + s * 32 + lane];
        }
        for (int t = 0; t < SLEN; ++t) {
            __syncthreads();   // barrier #t: red[t&1] ready
            if (act) {
                const int par = t & 1;
                float pre[4];
#pragma unroll
                for (int g = 0; g < 4; g++) {
                    int rl = g * 32 + lane;
                    pre[g] = ((red[par][rl][0] + red[par][rl][1])
                            + (red[par][rl][2] + red[par][rl][3])) + xp4[g];
                }
                float iv  = sigm_f(pre[0]);
                float fvv = sigm_f(pre[1]);
                float gv  = tanh_f(pre[2]);
                float ov  = sigm_f(pre[3]);
                c_state = fvv * c_state + iv * gv;
                float h = ov * tanh_f(c_state);
                int hglob = s * 32 + lane;
                // publish FIRST — the only thing on the critical path
                unsigned long long pv = ((unsigned long long)(unsigned)(t + 1) << 32)
                                      | (unsigned long long)__float_as_uint(h);
                __hip_atomic_store(mbase + ((t + 1) & 1) * 512 + hglob, pv,
                                   __ATOMIC_RELAXED, __HIP_MEMORY_SCOPE_AGENT);
                // tail: off critical path
                int tpos = dir ? (SLEN - 1 - t) : t;
                lstm_out[(size_t)tpos * 512 + dir * HDIM + hglob] = h;
                if ((t + 1) < SLEN) {
                    int tpos1 = dir ? (SLEN - 2 - t) : (t + 1);
                    const float* base = xp + ((size_t)dir * SLEN + tpos1) * G4;
#pragma unroll
                    for (int g = 0; g < 4; g++) xp4[g] = base[(g << 8) + s * 32 + lane];
                }
            }
        }
    }
}

// ------------------------------------------------------------------
// K3: feats[t][n] = lstm[t] . W_out[n] + b_out[n]
// ------------------------------------------------------------------
__global__ __launch_bounds__(256) void feats_kernel(
    const float* __restrict__ lstm, const float* __restrict__ W_out,
    const float* __restrict__ b_out, float* __restrict__ feats)
{
    int gid = blockIdx.x * 256 + threadIdx.x;
    if (gid >= SLEN * NT) return;
    int t = gid / NT, n = gid - t * NT;
    const float4* hr = (const float4*)(lstm + (size_t)t * 512);
    const float4* wr = (const float4*)(W_out + (size_t)n * 512);
    float acc = 0.f;
#pragma unroll 8
    for (int k = 0; k < 128; k++) {
        float4 a = hr[k], b = wr[k];
        acc += a.x * b.x + a.y * b.y + a.z * b.z + a.w * b.w;
    }
    feats[gid] = acc + b_out[n];
}

// ------------------------------------------------------------------
// K4: sequential Viterbi forward. 1 block, 64 threads (lanes 0..23 live).
// Single wave => lanes are lockstep; no __syncthreads needed — LDS
// write->read ordering within the wave is handled by lgkmcnt (compiler-
// inserted). Inner max via LDS broadcast (6 float4 reads), ascending-p
// strict-> first-max semantics (np.argmax).
// ------------------------------------------------------------------
__global__ __launch_bounds__(64) void viterbi_fwd_kernel(
    const float* __restrict__ feats, const float* __restrict__ trans,
    int* __restrict__ bp, float* __restrict__ score_out, int* __restrict__ blast)
{
    int lane = threadIdx.x;
    __shared__ __align__(16) float fvs[32];
    float Trow[NT];
    float tstop = NINF;
    float fv;
    if (lane < NT) {
#pragma unroll
        for (int p = 0; p < NT; p++) Trow[p] = trans[lane * NT + p];
        tstop = trans[TAG_STOP * NT + lane];
        fv = (lane == TAG_START) ? 0.f : NEGV;
    } else {
        fv = NINF;
#pragma unroll
        for (int p = 0; p < NT; p++) Trow[p] = NINF;
    }
    float fnext = (lane < NT) ? feats[lane] : 0.f;
    for (int t = 0; t < SLEN; t++) {
        float featv = fnext;
        if ((t + 1) < SLEN && lane < NT) fnext = feats[(t + 1) * NT + lane];
        if (lane < NT) fvs[lane] = fv;
        // single wave: ds_write visible after lgkmcnt (compiler-inserted);
        // lockstep lanes make a barrier unnecessary.
        float best = NINF; int arg = 0;
#pragma unroll
        for (int pq = 0; pq < 6; pq++) {
            float4 f4 = *(const float4*)&fvs[pq * 4];
            float sc;
            sc = f4.x + Trow[pq*4+0]; if (sc > best) { best = sc; arg = pq*4+0; }
            sc = f4.y + Trow[pq*4+1]; if (sc > best) { best = sc; arg = pq*4+1; }
            sc = f4.z + Trow[pq*4+2]; if (sc > best) { best = sc; arg = pq*4+2; }
            sc = f4.w + Trow[pq*4+3]; if (sc > best) { best = sc; arg = pq*4+3; }
        }
        if (lane < NT) bp[t * NT + lane] = arg;
        fv = best + featv;
    }
    float term = (lane < NT) ? (fv + tstop) : NINF;
    int idx = lane;
#pragma unroll
    for (int off = 32; off >= 1; off >>= 1) {
        float v2 = __shfl_xor(term, off);
        int   i2 = __shfl_xor(idx, off);
        if (v2 > term || (v2 == term && i2 < idx)) { term = v2; idx = i2; }
    }
    if (lane == 0) { score_out[0] = term; blast[0] = idx; }
}

// ------------------------------------------------------------------
// K5: per-chunk composed backtrace maps. 64 chunks x 64 steps.
// ------------------------------------------------------------------
__global__ __launch_bounds__(64) void bt_maps_kernel(
    const int* __restrict__ bp, int* __restrict__ maps)
{
    int c = blockIdx.x;
    __shared__ int bpl[64 * NT];
    for (int idx = threadIdx.x; idx < 64 * NT; idx += 64) bpl[idx] = bp[c * 64 * NT + idx];
    __syncthreads();
    if (threadIdx.x < NT) {
        int f = threadIdx.x;
#pragma unroll 1
        for (int k = 63; k >= 0; k--) f = bpl[k * NT + f];
        maps[c * NT + threadIdx.x] = f;
    }
}

// ------------------------------------------------------------------
// K6: combine chunk maps sequentially. evec[c] = path[64c+63].
// ------------------------------------------------------------------
__global__ __launch_bounds__(64) void bt_combine_kernel(
    const int* __restrict__ maps, const int* __restrict__ blast, int* __restrict__ evec)
{
    __shared__ int ml[64 * NT];
    for (int idx = threadIdx.x; idx < 64 * NT; idx += 64) ml[idx] = maps[idx];
    __syncthreads();
    if (threadIdx.x == 0) {
        int e = blast[0];
        evec[63] = e;
        for (int c = 63; c >= 1; c--) { e = ml[c * NT + e]; evec[c - 1] = e; }
    }
}

// ------------------------------------------------------------------
// K7: re-expand each chunk and emit path tags as floats.
// ------------------------------------------------------------------
__global__ __launch_bounds__(64) void bt_emit_kernel(
    const int* __restrict__ bp, const int* __restrict__ evec, float* __restrict__ out_path)
{
    int c = blockIdx.x;
    __shared__ int bpl[64 * NT];
    for (int idx = threadIdx.x; idx < 64 * NT; idx += 64) bpl[idx] = bp[c * 64 * NT + idx];
    __syncthreads();
    if (threadIdx.x == 0) {
        int f = evec[c];
        out_path[c * 64 + 63] = (float)f;
        for (int t = 62; t >= 0; t--) {
            f = bpl[(t + 1) * NT + f];
            out_path[c * 64 + t] = (float)f;
        }
    }
}

extern "C" void kernel_launch(void* const* d_in, const int* in_sizes, int n_in,
                              void* d_out, int out_size, void* d_ws, size_t ws_size,
                              hipStream_t stream)
{
    const int*   sent   = (const int*)d_in[0];
    const float* h0     = (const float*)d_in[1];
    const float* c0     = (const float*)d_in[2];
    const float* emb    = (const float*)d_in[3];
    const float* W_ih_f = (const float*)d_in[4];
    const float* W_hh_f = (const float*)d_in[5];
    const float* b_ih_f = (const float*)d_in[6];
    const float* b_hh_f = (const float*)d_in[7];
    const float* W_ih_b = (const float*)d_in[8];
    const float* W_hh_b = (const float*)d_in[9];
    const float* b_ih_b = (const float*)d_in[10];
    const float* b_hh_b = (const float*)d_in[11];
    const float* W_out  = (const float*)d_in[12];
    const float* b_out  = (const float*)d_in[13];
    const float* trans  = (const float*)d_in[14];

    char* ws = (char*)d_ws;
    float* xp    = (float*)(ws + OFF_XP);
    float* lstm  = (float*)(ws + OFF_LSTM);
    float* feats = (float*)(ws + OFF_FEATS);
    int*   bp    = (int*)  (ws + OFF_BP);
    unsigned long long* hpub = (unsigned long long*)(ws + OFF_BP);   // 8 KiB (dead until K4)
    int*   maps  = (int*)  (ws + OFF_MAPS);
    int*   evec  = (int*)  (ws + OFF_EVEC);
    int*   blast = (int*)  (ws + OFF_BLAST);

    float* outf = (float*)d_out;

    init_zero_kernel<<<2, 512, 0, stream>>>(hpub);    // zero 1024 mailbox slots
    xp_gemm_kernel<<<2048, 256, 0, stream>>>(sent, emb, W_ih_f, b_ih_f, b_hh_f,
                                             W_ih_b, b_ih_b, b_hh_b, xp);
    lstm_scan_kernel<<<64, 576, 0, stream>>>(xp, h0, c0, W_hh_f, W_hh_b, lstm, hpub);
    feats_kernel<<<384, 256, 0, stream>>>(lstm, W_out, b_out, feats);
    viterbi_fwd_kernel<<<1, 64, 0, stream>>>(feats, trans, bp, outf, blast);
    bt_maps_kernel<<<64, 64, 0, stream>>>(bp, maps);
    bt_combine_kernel<<<1, 64, 0, stream>>>(maps, blast, evec);
    bt_emit_kernel<<<64, 64, 0, stream>>>(bp, evec, outf + 1);
}